// Round 3
// baseline (708.214 us; speedup 1.0000x reference)
//
#include <hip/hip_runtime.h>
#include <stdint.h>

// Correlation_29609504538974: 6-level spatial correlation, patch 3x3 + leaky_relu(corr/C).
// out_l[b, t, y, x] = leaky( (1/C) * sum_c f1[b,c,y,x] * f2[b,c,y+di,x+dj] ),
//   di,dj in {-1,0,1}, t=(di+1)*3+(dj+1); f1 = x_l, f2 = x_pre_l. Zero pad outside.
//
// R3 FIX: setup_inputs() builds the dict INTERLEAVED: d_in[2i]=x_pre_i, d_in[2i+1]=x_i.
//   R1/R2 assumed grouped order and read 128 MB from a 1 MB buffer -> HSA fault/abort.
//   Runtime guard: interleaved iff in_sizes[0]==in_sizes[1] (both level-0 tensors).
//
// Phase A: zero-fill d_out (3 MB).
// Phase B: wave = (64 consecutive pixels) x (channel chunk); lane owns one pixel,
//   loops channels: 1 coalesced f1 load + 9 clamped f2 tap loads + 9 FMAs.
//   Valid-tap accumulators atomicAdd'ed into d_out (device-scope fp32, exact).
//   Invalid (padded) taps write nothing — output stays 0 = reference value.
// Phase C: in-place finalize out[e] = leaky(out[e] * 1/C).

struct Lv1 {
  const float* f1;
  const float* f2;
  int C, ss;           // channels, log2(S)
  int csize;           // channels per chunk
  uint32_t pxwaves;    // B*S*S/64
  uint32_t jobs_end;   // cumulative job count (exclusive end)
  uint32_t out_off;    // element offset of this level in d_out
};
struct P1 { Lv1 lv[6]; uint32_t total_jobs; };

__global__ __launch_bounds__(256) void corr_zero(float4* __restrict__ out, uint32_t n4) {
  const uint32_t e = blockIdx.x * 256u + threadIdx.x;
  if (e < n4) out[e] = make_float4(0.f, 0.f, 0.f, 0.f);
}

__global__ __launch_bounds__(256) void corr_acc(P1 p, float* __restrict__ out) {
  const uint32_t wid = ((blockIdx.x << 8) + threadIdx.x) >> 6;
  const int lane = threadIdx.x & 63;
  if (wid >= p.total_jobs) return;

  int l = 0;
#pragma unroll
  for (int i = 0; i < 5; ++i) l += (wid >= p.lv[i].jobs_end) ? 1 : 0;
  const Lv1 L = p.lv[l];
  const uint32_t lbase = (l == 0) ? 0u : p.lv[l - 1].jobs_end;
  const uint32_t local = wid - lbase;
  const uint32_t chunk = local / L.pxwaves;
  const uint32_t pxw = local - chunk * L.pxwaves;

  const int ss = L.ss;
  const int S = 1 << ss;
  const int S2 = 1 << (2 * ss);
  const uint32_t pix = (pxw << 6) + (uint32_t)lane;  // linear over B*S*S
  const uint32_t b = pix >> (2 * ss);
  const uint32_t yx = pix & (uint32_t)(S2 - 1);
  const int y = (int)(yx >> ss), x = (int)(yx & (uint32_t)(S - 1));

  int off[9];
  float acc[9];
  uint32_t mb = 0;
#pragma unroll
  for (int t = 0; t < 9; ++t) {
    const int di = t / 3 - 1, dj = t % 3 - 1;
    const int yy = y + di, xx = x + dj;
    const bool v = (yy >= 0) & (yy < S) & (xx >= 0) & (xx < S);
    int o = yy * S + xx;
    o = o < 0 ? 0 : (o > S2 - 1 ? S2 - 1 : o);  // clamped in-plane; garbage ok (masked)
    off[t] = o;
    if (v) mb |= (1u << t);
    acc[t] = 0.f;
  }

  const uint32_t c0 = chunk * (uint32_t)L.csize;
  const size_t pbase = ((size_t)(b * (uint32_t)L.C + c0)) << (2 * ss);
  const float* f1p = L.f1 + pbase + yx;
  const float* f2p = L.f2 + pbase;

#pragma unroll 2
  for (int j = 0; j < L.csize; ++j) {
    const float a = f1p[0];
#pragma unroll
    for (int t = 0; t < 9; ++t) acc[t] = fmaf(a, f2p[off[t]], acc[t]);
    f1p += S2;
    f2p += S2;
  }

  // out element: out_off + ((b*9 + t) << 2ss) + yx
  float* obase = out + L.out_off + (((size_t)b * 9u) << (2 * ss)) + yx;
#pragma unroll
  for (int t = 0; t < 9; ++t) {
    if ((mb >> t) & 1u) atomicAdd(obase + ((size_t)t << (2 * ss)), acc[t]);
  }
}

struct P3 {
  uint32_t ends[6];
  float invC[6];
  uint32_t total;
};

__global__ __launch_bounds__(256) void corr_fin(P3 p, float* __restrict__ out) {
  const uint32_t e = blockIdx.x * 256u + threadIdx.x;
  if (e >= p.total) return;
  int l = 0;
#pragma unroll
  for (int i = 0; i < 5; ++i) l += (e >= p.ends[i]) ? 1 : 0;
  const float s = out[e] * p.invC[l];
  out[e] = s >= 0.f ? s : 0.01f * s;
}

extern "C" void kernel_launch(void* const* d_in, const int* in_sizes, int n_in,
                              void* d_out, int out_size, void* d_ws, size_t ws_size,
                              hipStream_t stream) {
  static const int CH[6] = {512, 1024, 512, 256, 256, 256};
  static const int LG[6] = {6, 5, 4, 3, 2, 1};
  static const int CK[6] = {4, 16, 32, 32, 64, 64};  // channel chunks per level

  // Dict order from setup_inputs() is interleaved (x_pre0, x0, x_pre1, x1, ...).
  // Detect at runtime: level-0 pair has equal sizes; grouped order would have
  // in_sizes[1] (x_pre1) != in_sizes[0] (x_pre0).
  const bool interleaved = (n_in >= 2) && (in_sizes[0] == in_sizes[1]);

  P1 p1;
  P3 p3;
  uint32_t jobs = 0, oend = 0;
  for (int i = 0; i < 6; ++i) {
    const int S = 1 << LG[i];
    const uint32_t npix = 16u * (uint32_t)(S * S);  // B=16
    const uint32_t pxw = npix >> 6;
    const int i_pre = interleaved ? (2 * i) : i;
    const int i_cur = interleaved ? (2 * i + 1) : (6 + i);
    p1.lv[i].f1 = (const float*)d_in[i_cur];   // x_i   (feat1)
    p1.lv[i].f2 = (const float*)d_in[i_pre];   // x_pre_i (feat2)
    p1.lv[i].C = CH[i];
    p1.lv[i].ss = LG[i];
    p1.lv[i].csize = CH[i] / CK[i];
    p1.lv[i].pxwaves = pxw;
    jobs += (uint32_t)CK[i] * pxw;
    p1.lv[i].jobs_end = jobs;
    p1.lv[i].out_off = oend;
    oend += 9u * npix;
    p3.ends[i] = oend;
    p3.invC[i] = 1.0f / (float)CH[i];
  }
  p1.total_jobs = jobs;
  p3.total = oend;

  const uint32_t n4 = oend / 4u;  // oend = 786240, divisible by 4
  const uint32_t gz = (n4 + 255u) / 256u;
  const uint32_t g1 = (jobs * 64u + 255u) / 256u;
  const uint32_t g3 = (oend + 255u) / 256u;

  corr_zero<<<gz, 256, 0, stream>>>((float4*)d_out, n4);
  corr_acc<<<g1, 256, 0, stream>>>(p1, (float*)d_out);
  corr_fin<<<g3, 256, 0, stream>>>(p3, (float*)d_out);
}

// Round 4
// 582.373 us; speedup vs baseline: 1.2161x; 1.2161x over previous
//
#include <hip/hip_runtime.h>
#include <stdint.h>

// Correlation_29609504538974: 6-level spatial correlation, patch 3x3 + leaky_relu(corr/C).
// out_l[b, t, y, x] = leaky( (1/C) * sum_c f1[b,c,y,x] * f2[b,c,y+di,x+dj] ),
//   t=(di+1)*3+(dj+1); f1 = x_l (d_in[2l+1]), f2 = x_pre_l (d_in[2l]). Zero pad outside.
//
// R4: R3 was latency-bound (451 us @ 656 GB/s, VALUBusy 8.8%) — 10 scalar dword
// loads per channel per pixel. Now levels 0..2 (S>=16, 99.7% of bytes) use a
// vectorized kernel: lane owns 4 consecutive pixels; per channel: 1 f1 dwordx4 +
// 3 f2 row dwordx4 loads; dj=+-1 taps via __shfl of neighbor lane's edge element.
// 36 accumulators, boundary taps masked once at the end (shuffle garbage at row
// edges only ever lands in masked accumulators). Levels 3..5 keep the scalar path.
// Phase A: zero d_out. Phase B: vec + scalar accumulate (atomicAdd fp32, exact).
// Phase C: in-place scale + leaky.

struct LvV {
  const float* f1;
  const float* f2;
  int C, ss;           // channels, log2(S)
  int csize;           // channels per chunk
  uint32_t tiles;      // B*S*S/256 pixel tiles
  uint32_t jobs_end;   // cumulative wave-job count
  uint32_t out_off;
};
struct PV { LvV lv[3]; uint32_t total_jobs; };

struct LvS {
  const float* f1;
  const float* f2;
  int C, ss;
  int csize;
  uint32_t pxwaves;    // B*S*S/64
  uint32_t jobs_end;
  uint32_t out_off;
};
struct PS { LvS lv[3]; uint32_t total_jobs; };

__global__ __launch_bounds__(256) void corr_zero(float4* __restrict__ out, uint32_t n4) {
  const uint32_t e = blockIdx.x * 256u + threadIdx.x;
  if (e < n4) out[e] = make_float4(0.f, 0.f, 0.f, 0.f);
}

__global__ __launch_bounds__(256) void corr_vec(PV p, float* __restrict__ out) {
  const uint32_t wid = ((blockIdx.x << 8) + threadIdx.x) >> 6;
  const int lane = threadIdx.x & 63;
  if (wid >= p.total_jobs) return;

  int l = 0;
#pragma unroll
  for (int i = 0; i < 2; ++i) l += (wid >= p.lv[i].jobs_end) ? 1 : 0;
  const LvV L = p.lv[l];
  const uint32_t lbase = (l == 0) ? 0u : p.lv[l - 1].jobs_end;
  const uint32_t local = wid - lbase;
  const uint32_t chunk = local / L.tiles;
  const uint32_t tile = local - chunk * L.tiles;

  const int ss = L.ss;
  const int S = 1 << ss;
  const int S2 = 1 << (2 * ss);
  const uint32_t pix0 = (tile << 8) + (uint32_t)(lane << 2);  // 4 consecutive pixels
  const uint32_t b = pix0 >> (2 * ss);
  const uint32_t yx = pix0 & (uint32_t)(S2 - 1);
  const int y = (int)(yx >> ss);
  const int x0 = (int)(yx & (uint32_t)(S - 1));  // multiple of 4

  const uint32_t c0 = chunk * (uint32_t)L.csize;
  const size_t pbase = ((size_t)(b * (uint32_t)L.C + c0)) << (2 * ss);

  const float* f1p = L.f1 + pbase + yx;
  const float* f2b = L.f2 + pbase;
  int rowoff[3];
#pragma unroll
  for (int r = 0; r < 3; ++r) {
    int yy = y + r - 1;
    yy = yy < 0 ? 0 : (yy > S - 1 ? S - 1 : yy);  // clamped; garbage masked later
    rowoff[r] = yy * S + x0;
  }

  float acc[3][3][4];
#pragma unroll
  for (int r = 0; r < 3; ++r)
#pragma unroll
    for (int d = 0; d < 3; ++d)
#pragma unroll
      for (int e = 0; e < 4; ++e) acc[r][d][e] = 0.f;

#pragma unroll 2
  for (int j = 0; j < L.csize; ++j) {
    const float4 a4 = *(const float4*)f1p;
    const float av[4] = {a4.x, a4.y, a4.z, a4.w};
#pragma unroll
    for (int r = 0; r < 3; ++r) {
      const float4 w = *(const float4*)(f2b + rowoff[r]);
      const float pw = __shfl_up(w.w, 1);    // prev lane's last elem (row-edge garbage masked)
      const float nx = __shfl_down(w.x, 1);  // next lane's first elem
      const float tm[4] = {pw, w.x, w.y, w.z};
      const float tz[4] = {w.x, w.y, w.z, w.w};
      const float tp[4] = {w.y, w.z, w.w, nx};
#pragma unroll
      for (int e = 0; e < 4; ++e) {
        acc[r][0][e] = fmaf(av[e], tm[e], acc[r][0][e]);
        acc[r][1][e] = fmaf(av[e], tz[e], acc[r][1][e]);
        acc[r][2][e] = fmaf(av[e], tp[e], acc[r][2][e]);
      }
    }
    f1p += S2;
    f2b += S2;
  }

  float* obase = out + L.out_off + (((size_t)b * 9u) << (2 * ss)) + yx;
#pragma unroll
  for (int r = 0; r < 3; ++r) {
    const int yy = y + r - 1;
    const bool vy = (yy >= 0) & (yy < S);
#pragma unroll
    for (int d = 0; d < 3; ++d) {
      const int t = r * 3 + d;
      float* op = obase + ((size_t)t << (2 * ss));
#pragma unroll
      for (int e = 0; e < 4; ++e) {
        const int xx = x0 + e + d - 1;
        if (vy & (xx >= 0) & (xx < S)) atomicAdd(op + e, acc[r][d][e]);
      }
    }
  }
}

__global__ __launch_bounds__(256) void corr_scal(PS p, float* __restrict__ out) {
  const uint32_t wid = ((blockIdx.x << 8) + threadIdx.x) >> 6;
  const int lane = threadIdx.x & 63;
  if (wid >= p.total_jobs) return;

  int l = 0;
#pragma unroll
  for (int i = 0; i < 2; ++i) l += (wid >= p.lv[i].jobs_end) ? 1 : 0;
  const LvS L = p.lv[l];
  const uint32_t lbase = (l == 0) ? 0u : p.lv[l - 1].jobs_end;
  const uint32_t local = wid - lbase;
  const uint32_t chunk = local / L.pxwaves;
  const uint32_t pxw = local - chunk * L.pxwaves;

  const int ss = L.ss;
  const int S = 1 << ss;
  const int S2 = 1 << (2 * ss);
  const uint32_t pix = (pxw << 6) + (uint32_t)lane;
  const uint32_t b = pix >> (2 * ss);
  const uint32_t yx = pix & (uint32_t)(S2 - 1);
  const int y = (int)(yx >> ss), x = (int)(yx & (uint32_t)(S - 1));

  int off[9];
  float acc[9];
  uint32_t mb = 0;
#pragma unroll
  for (int t = 0; t < 9; ++t) {
    const int di = t / 3 - 1, dj = t % 3 - 1;
    const int yy = y + di, xx = x + dj;
    const bool v = (yy >= 0) & (yy < S) & (xx >= 0) & (xx < S);
    int o = yy * S + xx;
    o = o < 0 ? 0 : (o > S2 - 1 ? S2 - 1 : o);
    off[t] = o;
    if (v) mb |= (1u << t);
    acc[t] = 0.f;
  }

  const uint32_t c0 = chunk * (uint32_t)L.csize;
  const size_t pbase = ((size_t)(b * (uint32_t)L.C + c0)) << (2 * ss);
  const float* f1p = L.f1 + pbase + yx;
  const float* f2p = L.f2 + pbase;

#pragma unroll 2
  for (int j = 0; j < L.csize; ++j) {
    const float a = f1p[0];
#pragma unroll
    for (int t = 0; t < 9; ++t) acc[t] = fmaf(a, f2p[off[t]], acc[t]);
    f1p += S2;
    f2p += S2;
  }

  float* obase = out + L.out_off + (((size_t)b * 9u) << (2 * ss)) + yx;
#pragma unroll
  for (int t = 0; t < 9; ++t) {
    if ((mb >> t) & 1u) atomicAdd(obase + ((size_t)t << (2 * ss)), acc[t]);
  }
}

struct P3 {
  uint32_t ends[6];
  float invC[6];
  uint32_t total;
};

__global__ __launch_bounds__(256) void corr_fin(P3 p, float* __restrict__ out) {
  const uint32_t e = blockIdx.x * 256u + threadIdx.x;
  if (e >= p.total) return;
  int l = 0;
#pragma unroll
  for (int i = 0; i < 5; ++i) l += (e >= p.ends[i]) ? 1 : 0;
  const float s = out[e] * p.invC[l];
  out[e] = s >= 0.f ? s : 0.01f * s;
}

extern "C" void kernel_launch(void* const* d_in, const int* in_sizes, int n_in,
                              void* d_out, int out_size, void* d_ws, size_t ws_size,
                              hipStream_t stream) {
  static const int CH[6] = {512, 1024, 512, 256, 256, 256};
  static const int LG[6] = {6, 5, 4, 3, 2, 1};
  static const int CKV[3] = {16, 32, 32};  // chunks, levels 0..2 (vec)
  static const int CKS[3] = {32, 64, 64};  // chunks, levels 3..5 (scalar)

  // setup_inputs() dict order is interleaved: d_in[2i]=x_pre_i, d_in[2i+1]=x_i.
  const bool interleaved = (n_in >= 2) && (in_sizes[0] == in_sizes[1]);

  PV pv;
  PS ps;
  P3 p3;
  uint32_t vjobs = 0, sjobs = 0, oend = 0;
  for (int i = 0; i < 6; ++i) {
    const int S = 1 << LG[i];
    const uint32_t npix = 16u * (uint32_t)(S * S);  // B=16
    const int i_pre = interleaved ? (2 * i) : i;
    const int i_cur = interleaved ? (2 * i + 1) : (6 + i);
    const float* f1 = (const float*)d_in[i_cur];
    const float* f2 = (const float*)d_in[i_pre];
    if (i < 3) {
      pv.lv[i].f1 = f1;
      pv.lv[i].f2 = f2;
      pv.lv[i].C = CH[i];
      pv.lv[i].ss = LG[i];
      pv.lv[i].csize = CH[i] / CKV[i];
      pv.lv[i].tiles = npix >> 8;
      vjobs += (uint32_t)CKV[i] * (npix >> 8);
      pv.lv[i].jobs_end = vjobs;
      pv.lv[i].out_off = oend;
    } else {
      const int k = i - 3;
      ps.lv[k].f1 = f1;
      ps.lv[k].f2 = f2;
      ps.lv[k].C = CH[i];
      ps.lv[k].ss = LG[i];
      ps.lv[k].csize = CH[i] / CKS[k];
      ps.lv[k].pxwaves = npix >> 6;
      sjobs += (uint32_t)CKS[k] * (npix >> 6);
      ps.lv[k].jobs_end = sjobs;
      ps.lv[k].out_off = oend;
    }
    oend += 9u * npix;
    p3.ends[i] = oend;
    p3.invC[i] = 1.0f / (float)CH[i];
  }
  pv.total_jobs = vjobs;
  ps.total_jobs = sjobs;
  p3.total = oend;

  const uint32_t n4 = oend / 4u;  // 786240 divisible by 4
  const uint32_t gz = (n4 + 255u) / 256u;
  const uint32_t gv = (vjobs * 64u + 255u) / 256u;
  const uint32_t gs = (sjobs * 64u + 255u) / 256u;
  const uint32_t g3 = (oend + 255u) / 256u;

  corr_zero<<<gz, 256, 0, stream>>>((float4*)d_out, n4);
  corr_vec<<<gv, 256, 0, stream>>>(pv, (float*)d_out);
  corr_scal<<<gs, 256, 0, stream>>>(ps, (float*)d_out);
  corr_fin<<<g3, 256, 0, stream>>>(p3, (float*)d_out);
}